// Round 1
// baseline (244.881 us; speedup 1.0000x reference)
//
#include <hip/hip_runtime.h>
#include <math.h>
#include <float.h>

#define B_ 2
#define T_ 384
#define D_ 512
#define H_ 8
#define HD_ 64
#define K_ 48
#define LN_EPS 1e-5f

// ---------------------------------------------------------------- transpose
__global__ __launch_bounds__(256) void k_transpose(const float* __restrict__ in,
                                                   float* __restrict__ out,
                                                   int R, int C) {
    int idx = blockIdx.x * 256 + threadIdx.x;
    if (idx < R * C) {
        int r = idx / C, c = idx - r * C;
        out[c * R + r] = in[idx];
    }
}

// ---------------------------------------------------- per-token superposition
// alpha = softmax(x @ g_w.T + g_b); hd = sum_h alpha[h]*x[h*64+k];
// xs = hd @ sp_w.T + sp_b     (spT is sp_w transposed: [HD][D])
__global__ __launch_bounds__(256) void k_super(const float* __restrict__ x,
                                               const float* __restrict__ g_w,
                                               const float* __restrict__ g_b,
                                               const float* __restrict__ spT,
                                               const float* __restrict__ sp_b,
                                               float* __restrict__ xs) {
    int token = blockIdx.x;
    int tid = threadIdx.x;
    __shared__ float xsh[D_];
    __shared__ float red[256];
    __shared__ float logits[H_];
    __shared__ float hd[HD_];
    const float* xt = x + (size_t)token * D_;
    xsh[tid] = xt[tid];
    xsh[tid + 256] = xt[tid + 256];
    __syncthreads();
    // 8 groups of 32 threads, one per head
    int g = tid >> 5, lane = tid & 31;
    float p = 0.f;
    for (int k = lane; k < D_; k += 32) p += xsh[k] * g_w[g * D_ + k];
    red[tid] = p;
    __syncthreads();
    for (int s = 16; s > 0; s >>= 1) {
        if (lane < s) red[tid] += red[tid + s];
        __syncthreads();
    }
    if (lane == 0) logits[g] = red[tid] + g_b[g];
    __syncthreads();
    // softmax over 8 heads, computed redundantly per thread
    float m = logits[0];
#pragma unroll
    for (int h = 1; h < H_; ++h) m = fmaxf(m, logits[h]);
    float e[H_];
    float sum = 0.f;
#pragma unroll
    for (int h = 0; h < H_; ++h) { e[h] = expf(logits[h] - m); sum += e[h]; }
    float inv = 1.f / sum;
    if (tid < HD_) {
        float v = 0.f;
#pragma unroll
        for (int h = 0; h < H_; ++h) v += e[h] * inv * xsh[h * HD_ + tid];
        hd[tid] = v;
    }
    __syncthreads();
    int d0 = tid, d1 = tid + 256;
    float a0 = sp_b[d0], a1 = sp_b[d1];
    for (int k = 0; k < HD_; ++k) {
        float hk = hd[k];
        a0 += spT[k * D_ + d0] * hk;
        a1 += spT[k * D_ + d1] * hk;
    }
    xs[(size_t)token * D_ + d0] = a0;
    xs[(size_t)token * D_ + d1] = a1;
}

// ---------------------------------------------------------- gate = sigmoid GEMM
// 4 tokens per block; gT is gate_w transposed [k][d]
__global__ __launch_bounds__(256) void k_gate(const float* __restrict__ xs,
                                              const float* __restrict__ gT,
                                              const float* __restrict__ gate_b,
                                              float* __restrict__ gate) {
    int t0 = blockIdx.x * 4;
    int tid = threadIdx.x;
    __shared__ float xsh[4][D_];
    for (int i = tid; i < 4 * D_; i += 256)
        ((float*)xsh)[i] = xs[(size_t)t0 * D_ + i];
    __syncthreads();
    int d0 = tid, d1 = tid + 256;
    float b0 = gate_b[d0], b1 = gate_b[d1];
    float acc[4][2];
#pragma unroll
    for (int j = 0; j < 4; ++j) { acc[j][0] = b0; acc[j][1] = b1; }
    for (int k = 0; k < D_; ++k) {
        float w0 = gT[k * D_ + d0], w1 = gT[k * D_ + d1];
#pragma unroll
        for (int j = 0; j < 4; ++j) {
            acc[j][0] += xsh[j][k] * w0;
            acc[j][1] += xsh[j][k] * w1;
        }
    }
#pragma unroll
    for (int j = 0; j < 4; ++j) {
        gate[(size_t)(t0 + j) * D_ + d0] = 1.f / (1.f + expf(-acc[j][0]));
        gate[(size_t)(t0 + j) * D_ + d1] = 1.f / (1.f + expf(-acc[j][1]));
    }
}

// ------------------------------------------------------- scores Gram matrix
// scores[b,i,j] = sqrt(sum_d gate[b,i,d]^2 * gate[b,j,d]^2)
__global__ __launch_bounds__(256) void k_scores(const float* __restrict__ gate,
                                                float* __restrict__ scores) {
    int b = blockIdx.z;
    int i0 = blockIdx.y * 32, j0 = blockIdx.x * 32;
    int tid = threadIdx.x;
    int tx = tid & 31, ty = tid >> 5;  // ty in 0..7
    __shared__ float Ash[32][33];
    __shared__ float Bsh[32][33];
    float acc[4] = {0.f, 0.f, 0.f, 0.f};
    const float* gb = gate + (size_t)b * T_ * D_;
    for (int k0 = 0; k0 < D_; k0 += 32) {
        for (int n = tid; n < 1024; n += 256) {
            int r = n >> 5, c = n & 31;
            float a = gb[(size_t)(i0 + r) * D_ + k0 + c];
            Ash[r][c] = a * a;
            float bb = gb[(size_t)(j0 + r) * D_ + k0 + c];
            Bsh[r][c] = bb * bb;
        }
        __syncthreads();
#pragma unroll
        for (int kk = 0; kk < 32; ++kk) {
            float bv = Bsh[tx][kk];
#pragma unroll
            for (int r = 0; r < 4; ++r) acc[r] += Ash[ty + 8 * r][kk] * bv;
        }
        __syncthreads();
    }
#pragma unroll
    for (int r = 0; r < 4; ++r)
        scores[((size_t)b * T_ + (i0 + ty + 8 * r)) * T_ + j0 + tx] = sqrtf(acc[r]);
}

// ------------------------------------------------- top-K selection + entangle
// iterative max-select (ties -> lower index, matching jax.lax.top_k), then
// x_out[i,d] = xs[i,d] + gate[i,d] * sum_{j in sel} gate[j,d]  (in-place on xs)
__global__ __launch_bounds__(256) void k_topk_ent(const float* __restrict__ scores,
                                                  const float* __restrict__ gate,
                                                  float* __restrict__ xs) {
    int i = blockIdx.x, b = blockIdx.y;
    int tid = threadIdx.x;
    __shared__ float sc[T_];
    __shared__ int sel[K_];
    __shared__ float wv[4];
    __shared__ int wi[4];
    const float* srow = scores + ((size_t)b * T_ + i) * T_;
    sc[tid] = srow[tid];
    if (tid < T_ - 256) sc[tid + 256] = srow[tid + 256];
    __syncthreads();
    int wave = tid >> 6, lane = tid & 63;
    for (int it = 0; it < K_; ++it) {
        float v = sc[tid];
        int ix = tid;
        if (tid < T_ - 256) {
            float v2 = sc[tid + 256];
            if (v2 > v) { v = v2; ix = tid + 256; }
        }
#pragma unroll
        for (int off = 32; off > 0; off >>= 1) {
            float vo = __shfl_xor(v, off);
            int io = __shfl_xor(ix, off);
            if (vo > v || (vo == v && io < ix)) { v = vo; ix = io; }
        }
        if (lane == 0) { wv[wave] = v; wi[wave] = ix; }
        __syncthreads();
        if (tid == 0) {
            float bv = wv[0];
            int bi = wi[0];
#pragma unroll
            for (int w = 1; w < 4; ++w)
                if (wv[w] > bv || (wv[w] == bv && wi[w] < bi)) { bv = wv[w]; bi = wi[w]; }
            sel[it] = bi;
            sc[bi] = -FLT_MAX;
        }
        __syncthreads();
    }
    int d0 = tid, d1 = tid + 256;
    float s0 = 0.f, s1 = 0.f;
    const float* gb = gate + (size_t)b * T_ * D_;
    for (int n = 0; n < K_; ++n) {
        const float* gj = gb + (size_t)sel[n] * D_;
        s0 += gj[d0];
        s1 += gj[d1];
    }
    size_t base = ((size_t)b * T_ + i) * D_;
    float gi0 = gate[base + d0], gi1 = gate[base + d1];
    xs[base + d0] += gi0 * s0;
    xs[base + d1] += gi1 * s1;
}

// ------------------------------------------------------ final GEMM + LayerNorm
__device__ inline float block_sum256(float v, float* red4, int tid) {
#pragma unroll
    for (int off = 32; off > 0; off >>= 1) v += __shfl_xor(v, off);
    int wave = tid >> 6, lane = tid & 63;
    if (lane == 0) red4[wave] = v;
    __syncthreads();
    float r = red4[0] + red4[1] + red4[2] + red4[3];
    __syncthreads();
    return r;
}

__global__ __launch_bounds__(256) void k_out(const float* __restrict__ xo,
                                             const float* __restrict__ uT,
                                             const float* __restrict__ U_b,
                                             const float* __restrict__ ln_g,
                                             const float* __restrict__ ln_b,
                                             float* __restrict__ out) {
    int t0 = blockIdx.x * 4;
    int tid = threadIdx.x;
    __shared__ float xsh[4][D_];
    __shared__ float red4[4];
    for (int i = tid; i < 4 * D_; i += 256)
        ((float*)xsh)[i] = xo[(size_t)t0 * D_ + i];
    __syncthreads();
    int d0 = tid, d1 = tid + 256;
    float b0 = U_b[d0], b1 = U_b[d1];
    float acc[4][2];
#pragma unroll
    for (int j = 0; j < 4; ++j) { acc[j][0] = b0; acc[j][1] = b1; }
    for (int k = 0; k < D_; ++k) {
        float w0 = uT[k * D_ + d0], w1 = uT[k * D_ + d1];
#pragma unroll
        for (int j = 0; j < 4; ++j) {
            acc[j][0] += xsh[j][k] * w0;
            acc[j][1] += xsh[j][k] * w1;
        }
    }
    float lg0 = ln_g[d0], lg1 = ln_g[d1];
    float lb0 = ln_b[d0], lb1 = ln_b[d1];
#pragma unroll
    for (int j = 0; j < 4; ++j) {
        float s = block_sum256(acc[j][0] + acc[j][1], red4, tid);
        float mu = s * (1.f / D_);
        float c0 = acc[j][0] - mu, c1 = acc[j][1] - mu;
        float vs = block_sum256(c0 * c0 + c1 * c1, red4, tid);
        float var = vs * (1.f / D_);
        float inv = rsqrtf(var + LN_EPS);
        out[(size_t)(t0 + j) * D_ + d0] = lg0 * c0 * inv + lb0;
        out[(size_t)(t0 + j) * D_ + d1] = lg1 * c1 * inv + lb1;
    }
}

// --------------------------------------------------------------------- launch
extern "C" void kernel_launch(void* const* d_in, const int* in_sizes, int n_in,
                              void* d_out, int out_size, void* d_ws, size_t ws_size,
                              hipStream_t stream) {
    const float* x      = (const float*)d_in[0];
    const float* g_w    = (const float*)d_in[1];
    const float* g_b    = (const float*)d_in[2];
    const float* sp_w   = (const float*)d_in[3];
    const float* sp_b   = (const float*)d_in[4];
    const float* gate_w = (const float*)d_in[5];
    const float* gate_b = (const float*)d_in[6];
    const float* U_w    = (const float*)d_in[7];
    const float* U_b    = (const float*)d_in[8];
    const float* ln_g   = (const float*)d_in[9];
    const float* ln_b   = (const float*)d_in[10];

    float* ws     = (float*)d_ws;
    float* gT     = ws;                 // 512*512
    float* uT     = gT + 262144;        // 512*512
    float* spT    = uT + 262144;        // 64*512
    float* xs     = spT + 32768;        // 768*512 (x_super, then x_out in-place)
    float* gate   = xs + 393216;        // 768*512
    float* scores = gate + 393216;      // 2*384*384

    k_transpose<<<1024, 256, 0, stream>>>(gate_w, gT, 512, 512);
    k_transpose<<<1024, 256, 0, stream>>>(U_w, uT, 512, 512);
    k_transpose<<<128, 256, 0, stream>>>(sp_w, spT, 512, 64);
    k_super<<<B_ * T_, 256, 0, stream>>>(x, g_w, g_b, spT, sp_b, xs);
    k_gate<<<B_ * T_ / 4, 256, 0, stream>>>(xs, gT, gate_b, gate);
    k_scores<<<dim3(T_ / 32, T_ / 32, B_), 256, 0, stream>>>(gate, scores);
    k_topk_ent<<<dim3(T_, B_), 256, 0, stream>>>(scores, gate, xs);
    k_out<<<B_ * T_ / 4, 256, 0, stream>>>(xs, uT, U_b, ln_g, ln_b, (float*)d_out);
}

// Round 4
// 223.524 us; speedup vs baseline: 1.0955x; 1.0955x over previous
//
#include <hip/hip_runtime.h>
#include <math.h>
#include <float.h>

#define B_ 2
#define T_ 384
#define D_ 512
#define H_ 8
#define HD_ 64
#define K_ 48
#define LN_EPS 1e-5f

// ------------------------------------------------------- fused transposes
// gate_w (512x512) -> gT, U_w (512x512) -> uT, sp_w (512x64) -> spT[64][512]
__global__ __launch_bounds__(256) void k_transpose_all(
    const float* __restrict__ gate_w, const float* __restrict__ U_w,
    const float* __restrict__ sp_w, float* __restrict__ gT,
    float* __restrict__ uT, float* __restrict__ spT) {
    int idx = blockIdx.x * 256 + threadIdx.x;
    if (idx < 262144) {
        int r = idx >> 9, c = idx & 511;
        gT[c * 512 + r] = gate_w[idx];
    } else if (idx < 524288) {
        int i2 = idx - 262144;
        int r = i2 >> 9, c = i2 & 511;
        uT[c * 512 + r] = U_w[i2];
    } else if (idx < 557056) {
        int i3 = idx - 524288;
        int r = i3 >> 6, c = i3 & 63;   // sp_w[d=r][k=c]
        spT[c * 512 + r] = sp_w[i3];
    }
}

// ---------------------------------------------------- per-token superposition
__global__ __launch_bounds__(256) void k_super(const float* __restrict__ x,
                                               const float* __restrict__ g_w,
                                               const float* __restrict__ g_b,
                                               const float* __restrict__ spT,
                                               const float* __restrict__ sp_b,
                                               float* __restrict__ xs) {
    int token = blockIdx.x;
    int tid = threadIdx.x;
    __shared__ float xsh[D_];
    __shared__ float logits[H_];
    __shared__ float hd[HD_];
    const float* xt = x + (size_t)token * D_;
    ((float2*)xsh)[tid] = ((const float2*)xt)[tid];
    __syncthreads();
    // head dot products: head h = tid>>5, lane-in-group l = tid&31
    int h = tid >> 5, l = tid & 31;
    float p = 0.f;
#pragma unroll
    for (int it = 0; it < 16; ++it) {
        int k = l + it * 32;
        p += xsh[k] * g_w[h * D_ + k];
    }
#pragma unroll
    for (int off = 16; off > 0; off >>= 1) p += __shfl_xor(p, off);
    if (l == 0) logits[h] = p + g_b[h];
    __syncthreads();
    // softmax over 8 heads (redundant per thread)
    float m = logits[0];
#pragma unroll
    for (int hh = 1; hh < H_; ++hh) m = fmaxf(m, logits[hh]);
    float e[H_];
    float sum = 0.f;
#pragma unroll
    for (int hh = 0; hh < H_; ++hh) { e[hh] = expf(logits[hh] - m); sum += e[hh]; }
    float inv = 1.f / sum;
    if (tid < HD_) {
        float v = 0.f;
#pragma unroll
        for (int hh = 0; hh < H_; ++hh) v += e[hh] * inv * xsh[hh * HD_ + tid];
        hd[tid] = v;
    }
    __syncthreads();
    // xs[token] = hd @ spT + sp_b   (2 adjacent cols per thread)
    float2 acc = ((const float2*)sp_b)[tid];
#pragma unroll
    for (int ks = 0; ks < HD_ / 4; ++ks) {
        float4 h4 = ((const float4*)hd)[ks];
        float2 w0 = ((const float2*)spT)[(4 * ks + 0) * 256 + tid];
        float2 w1 = ((const float2*)spT)[(4 * ks + 1) * 256 + tid];
        float2 w2 = ((const float2*)spT)[(4 * ks + 2) * 256 + tid];
        float2 w3 = ((const float2*)spT)[(4 * ks + 3) * 256 + tid];
        acc.x += h4.x * w0.x + h4.y * w1.x + h4.z * w2.x + h4.w * w3.x;
        acc.y += h4.x * w0.y + h4.y * w1.y + h4.z * w2.y + h4.w * w3.y;
    }
    ((float2*)xs)[(size_t)token * 256 + tid] = acc;
}

// ---------------------------------------------------------- gate = sigmoid GEMM
// 4 tokens/block, 2 adjacent cols/thread, k unrolled by 4
__global__ __launch_bounds__(256) void k_gate(const float* __restrict__ xs,
                                              const float* __restrict__ gT,
                                              const float* __restrict__ gate_b,
                                              float* __restrict__ gate) {
    int t0 = blockIdx.x * 4;
    int tid = threadIdx.x;
    __shared__ float xsh[4][D_];
    ((float4*)xsh)[tid] = ((const float4*)(xs + (size_t)t0 * D_))[tid];
    ((float4*)xsh)[tid + 256] = ((const float4*)(xs + (size_t)t0 * D_))[tid + 256];
    __syncthreads();
    float2 bv = ((const float2*)gate_b)[tid];
    float2 acc[4] = {bv, bv, bv, bv};
    const float2* gT2 = (const float2*)gT;
    for (int k0 = 0; k0 < D_; k0 += 4) {
        float2 w0 = gT2[(k0 + 0) * 256 + tid];
        float2 w1 = gT2[(k0 + 1) * 256 + tid];
        float2 w2 = gT2[(k0 + 2) * 256 + tid];
        float2 w3 = gT2[(k0 + 3) * 256 + tid];
#pragma unroll
        for (int j = 0; j < 4; ++j) {
            float4 xv = *(const float4*)&xsh[j][k0];
            acc[j].x += xv.x * w0.x + xv.y * w1.x + xv.z * w2.x + xv.w * w3.x;
            acc[j].y += xv.x * w0.y + xv.y * w1.y + xv.z * w2.y + xv.w * w3.y;
        }
    }
#pragma unroll
    for (int j = 0; j < 4; ++j) {
        float2 o;
        o.x = 1.f / (1.f + expf(-acc[j].x));
        o.y = 1.f / (1.f + expf(-acc[j].y));
        ((float2*)gate)[(size_t)(t0 + j) * 256 + tid] = o;
    }
}

// ------------------------------------------------------- scores Gram matrix
// 64x64 output tile, 4x4 per thread, transposed-stage LDS + b128 reads
__global__ __launch_bounds__(256) void k_scores(const float* __restrict__ gate,
                                                float* __restrict__ scores) {
    int b = blockIdx.z;
    int i0 = blockIdx.y * 64, j0 = blockIdx.x * 64;
    int tid = threadIdx.x;
    int tx = tid & 15, ty = tid >> 4;
    __shared__ float Ash[16][68];
    __shared__ float Bsh[16][68];
    float acc[4][4];
#pragma unroll
    for (int r = 0; r < 4; ++r)
#pragma unroll
        for (int c = 0; c < 4; ++c) acc[r][c] = 0.f;
    const float* gb = gate + (size_t)b * T_ * D_;
    int sr = tid >> 2, sc4 = (tid & 3) * 4;
    for (int k0 = 0; k0 < D_; k0 += 16) {
        float4 av = *(const float4*)&gb[(size_t)(i0 + sr) * D_ + k0 + sc4];
        float4 bvv = *(const float4*)&gb[(size_t)(j0 + sr) * D_ + k0 + sc4];
        Ash[sc4 + 0][sr] = av.x * av.x;
        Ash[sc4 + 1][sr] = av.y * av.y;
        Ash[sc4 + 2][sr] = av.z * av.z;
        Ash[sc4 + 3][sr] = av.w * av.w;
        Bsh[sc4 + 0][sr] = bvv.x * bvv.x;
        Bsh[sc4 + 1][sr] = bvv.y * bvv.y;
        Bsh[sc4 + 2][sr] = bvv.z * bvv.z;
        Bsh[sc4 + 3][sr] = bvv.w * bvv.w;
        __syncthreads();
#pragma unroll
        for (int kk = 0; kk < 16; ++kk) {
            float4 a4 = *(const float4*)&Ash[kk][4 * ty];
            float4 b4 = *(const float4*)&Bsh[kk][4 * tx];
            float ar[4] = {a4.x, a4.y, a4.z, a4.w};
            float bc[4] = {b4.x, b4.y, b4.z, b4.w};
#pragma unroll
            for (int r = 0; r < 4; ++r)
#pragma unroll
                for (int c = 0; c < 4; ++c) acc[r][c] += ar[r] * bc[c];
        }
        __syncthreads();
    }
#pragma unroll
    for (int r = 0; r < 4; ++r) {
        float4 o;
        o.x = sqrtf(acc[r][0]);
        o.y = sqrtf(acc[r][1]);
        o.z = sqrtf(acc[r][2]);
        o.w = sqrtf(acc[r][3]);
        *(float4*)&scores[((size_t)b * T_ + (i0 + 4 * ty + r)) * T_ + j0 + 4 * tx] = o;
    }
}

// ------------------------------------------------- top-K selection + entangle
// one 64-lane wave per row; no barriers, no LDS. Ties -> lower index (JAX).
__global__ __launch_bounds__(256) void k_topk_ent(const float* __restrict__ scores,
                                                  const float* __restrict__ gate,
                                                  float* __restrict__ xs) {
    int tid = threadIdx.x;
    int wave = tid >> 6, lane = tid & 63;
    int row = blockIdx.x * 4 + wave;          // 0..767
    int b = row / T_;
    const float* srow = scores + (size_t)row * T_;
    float v[6];
#pragma unroll
    for (int q = 0; q < 6; ++q) v[q] = srow[q * 64 + lane];
    int keep = 0;  // lane it holds selected index of iteration it
    for (int it = 0; it < K_; ++it) {
        float bv = v[0];
        int bq = 0;
#pragma unroll
        for (int q = 1; q < 6; ++q)
            if (v[q] > bv) { bv = v[q]; bq = q; }   // strict > : lower q wins ties
        int bidx = bq * 64 + lane;
#pragma unroll
        for (int off = 1; off < 64; off <<= 1) {
            float ov = __shfl_xor(bv, off);
            int oi = __shfl_xor(bidx, off);
            if (ov > bv || (ov == bv && oi < bidx)) { bv = ov; bidx = oi; }
        }
        if (lane == (bidx & 63)) v[bidx >> 6] = -FLT_MAX;
        if (lane == it) keep = bidx;
    }
    // entangle: lane owns cols d = lane*8 .. lane*8+7
    float4 s0 = {0.f, 0.f, 0.f, 0.f}, s1 = {0.f, 0.f, 0.f, 0.f};
    const float* gb = gate + (size_t)b * T_ * D_;
    for (int n = 0; n < K_; ++n) {
        int j = __shfl(keep, n);
        const float4* gj = (const float4*)(gb + (size_t)j * D_ + lane * 8);
        float4 g0 = gj[0], g1 = gj[1];
        s0.x += g0.x; s0.y += g0.y; s0.z += g0.z; s0.w += g0.w;
        s1.x += g1.x; s1.y += g1.y; s1.z += g1.z; s1.w += g1.w;
    }
    size_t base = (size_t)row * D_ + lane * 8;
    const float4* gi = (const float4*)(gate + base);
    float4* xo = (float4*)(xs + base);
    float4 gi0 = gi[0], gi1 = gi[1];
    float4 x0 = xo[0], x1 = xo[1];
    x0.x += gi0.x * s0.x; x0.y += gi0.y * s0.y; x0.z += gi0.z * s0.z; x0.w += gi0.w * s0.w;
    x1.x += gi1.x * s1.x; x1.y += gi1.y * s1.y; x1.z += gi1.z * s1.z; x1.w += gi1.w * s1.w;
    xo[0] = x0;
    xo[1] = x1;
}

// ------------------------------------------------------ final GEMM + LayerNorm
__global__ __launch_bounds__(256) void k_out(const float* __restrict__ xo,
                                             const float* __restrict__ uT,
                                             const float* __restrict__ U_b,
                                             const float* __restrict__ ln_g,
                                             const float* __restrict__ ln_b,
                                             float* __restrict__ out) {
    int t0 = blockIdx.x * 4;
    int tid = threadIdx.x;
    __shared__ float xsh[4][D_];
    __shared__ float2 red4[4];
    ((float4*)xsh)[tid] = ((const float4*)(xo + (size_t)t0 * D_))[tid];
    ((float4*)xsh)[tid + 256] = ((const float4*)(xo + (size_t)t0 * D_))[tid + 256];
    __syncthreads();
    float2 bv = ((const float2*)U_b)[tid];
    float2 acc[4] = {bv, bv, bv, bv};
    const float2* uT2 = (const float2*)uT;
    for (int k0 = 0; k0 < D_; k0 += 4) {
        float2 w0 = uT2[(k0 + 0) * 256 + tid];
        float2 w1 = uT2[(k0 + 1) * 256 + tid];
        float2 w2 = uT2[(k0 + 2) * 256 + tid];
        float2 w3 = uT2[(k0 + 3) * 256 + tid];
#pragma unroll
        for (int j = 0; j < 4; ++j) {
            float4 xv = *(const float4*)&xsh[j][k0];
            acc[j].x += xv.x * w0.x + xv.y * w1.x + xv.z * w2.x + xv.w * w3.x;
            acc[j].y += xv.x * w0.y + xv.y * w1.y + xv.z * w2.y + xv.w * w3.y;
        }
    }
    float2 lg = ((const float2*)ln_g)[tid];
    float2 lb = ((const float2*)ln_b)[tid];
    int wv = tid >> 6, lane = tid & 63;
#pragma unroll
    for (int j = 0; j < 4; ++j) {
        float2 a = acc[j];
        float2 sv;
        sv.x = a.x + a.y;
        sv.y = a.x * a.x + a.y * a.y;
#pragma unroll
        for (int off = 32; off > 0; off >>= 1) {
            sv.x += __shfl_xor(sv.x, off);
            sv.y += __shfl_xor(sv.y, off);
        }
        if (lane == 0) red4[wv] = sv;
        __syncthreads();
        float s1 = red4[0].x + red4[1].x + red4[2].x + red4[3].x;
        float s2 = red4[0].y + red4[1].y + red4[2].y + red4[3].y;
        __syncthreads();
        float mu = s1 * (1.f / D_);
        float var = fmaxf(s2 * (1.f / D_) - mu * mu, 0.f);
        float inv = rsqrtf(var + LN_EPS);
        float2 o;
        o.x = lg.x * (a.x - mu) * inv + lb.x;
        o.y = lg.y * (a.y - mu) * inv + lb.y;
        ((float2*)out)[(size_t)(t0 + j) * 256 + tid] = o;
    }
}

// --------------------------------------------------------------------- launch
extern "C" void kernel_launch(void* const* d_in, const int* in_sizes, int n_in,
                              void* d_out, int out_size, void* d_ws, size_t ws_size,
                              hipStream_t stream) {
    const float* x      = (const float*)d_in[0];
    const float* g_w    = (const float*)d_in[1];
    const float* g_b    = (const float*)d_in[2];
    const float* sp_w   = (const float*)d_in[3];
    const float* sp_b   = (const float*)d_in[4];
    const float* gate_w = (const float*)d_in[5];
    const float* gate_b = (const float*)d_in[6];
    const float* U_w    = (const float*)d_in[7];
    const float* U_b    = (const float*)d_in[8];
    const float* ln_g   = (const float*)d_in[9];
    const float* ln_b   = (const float*)d_in[10];

    float* ws     = (float*)d_ws;
    float* gT     = ws;                 // 512*512
    float* uT     = gT + 262144;        // 512*512
    float* spT    = uT + 262144;        // 64*512
    float* xs     = spT + 32768;        // 768*512 (x_super, then x_out in-place)
    float* gate   = xs + 393216;        // 768*512
    float* scores = gate + 393216;      // 2*384*384

    k_transpose_all<<<2176, 256, 0, stream>>>(gate_w, U_w, sp_w, gT, uT, spT);
    k_super<<<B_ * T_, 256, 0, stream>>>(x, g_w, g_b, spT, sp_b, xs);
    k_gate<<<B_ * T_ / 4, 256, 0, stream>>>(xs, gT, gate_b, gate);
    k_scores<<<dim3(T_ / 64, T_ / 64, B_), 256, 0, stream>>>(gate, scores);
    k_topk_ent<<<B_ * T_ / 4, 256, 0, stream>>>(scores, gate, xs);
    k_out<<<B_ * T_ / 4, 256, 0, stream>>>(xs, uT, U_b, ln_g, ln_b, (float*)d_out);
}

// Round 5
// 213.902 us; speedup vs baseline: 1.1448x; 1.0450x over previous
//
#include <hip/hip_runtime.h>
#include <math.h>
#include <float.h>

#define B_ 2
#define T_ 384
#define D_ 512
#define H_ 8
#define HD_ 64
#define K_ 48
#define LN_EPS 1e-5f

// ----------------------------------------------- coalesced tiled transposes
// 32x32 LDS tiles, pad 33 to avoid bank conflicts. Blocks:
//   [0,256)   gate_w (512x512) -> gT[k][d]
//   [256,512) U_w    (512x512) -> uT[k][d]
//   [512,544) sp_w   (512x64)  -> spT[k][d]
__global__ __launch_bounds__(256) void k_prep(const float* __restrict__ gate_w,
                                              const float* __restrict__ U_w,
                                              const float* __restrict__ sp_w,
                                              float* __restrict__ gT,
                                              float* __restrict__ uT,
                                              float* __restrict__ spT) {
    __shared__ float t[32][33];
    int bid = blockIdx.x;
    const float* src;
    float* dst;
    int C, tr, tc;
    if (bid < 256) {
        src = gate_w; dst = gT; C = 512; tr = bid >> 4; tc = bid & 15;
    } else if (bid < 512) {
        int b2 = bid - 256;
        src = U_w; dst = uT; C = 512; tr = b2 >> 4; tc = b2 & 15;
    } else {
        int b3 = bid - 512;
        src = sp_w; dst = spT; C = 64; tr = b3 >> 1; tc = b3 & 1;
    }
    int r0 = tr * 32, c0 = tc * 32;
    int tx = threadIdx.x & 31, ty = threadIdx.x >> 5;
#pragma unroll
    for (int i = 0; i < 4; ++i)
        t[ty + 8 * i][tx] = src[(size_t)(r0 + ty + 8 * i) * C + c0 + tx];
    __syncthreads();
#pragma unroll
    for (int i = 0; i < 4; ++i)
        dst[(size_t)(c0 + ty + 8 * i) * 512 + r0 + tx] = t[tx][ty + 8 * i];
}

// --------------------------------- fused superposition + gate (4 tokens/block)
// Phase A: alpha=softmax(x@g_w.T+g_b); hd=sum_h alpha_h * x[h*64+:]; xs=hd@spT+sp_b
// Phase B: gate = sigmoid(xs @ gT + gate_b), xs read from LDS.
__global__ __launch_bounds__(256) void k_super_gate(
    const float* __restrict__ x, const float* __restrict__ g_w,
    const float* __restrict__ g_b, const float* __restrict__ spT,
    const float* __restrict__ sp_b, const float* __restrict__ gT,
    const float* __restrict__ gate_b, float* __restrict__ xs,
    float* __restrict__ gate) {
    int t0 = blockIdx.x * 4;
    int tid = threadIdx.x;
    __shared__ float xsh[4][D_];
    __shared__ float xss[4][D_];
    __shared__ float logits[4][H_];
    __shared__ float hd[4][HD_];
    // stage 4 token x vectors (float4, coalesced)
    ((float4*)&xsh[0][0])[tid] = ((const float4*)(x + (size_t)t0 * D_))[tid];
    ((float4*)&xsh[0][0])[tid + 256] = ((const float4*)(x + (size_t)t0 * D_))[tid + 256];
    __syncthreads();
    // head logits in one pass: tid = token*64 + head*8 + l8
    int tt = tid >> 6, hh = (tid >> 3) & 7, l8 = tid & 7;
    float p = 0.f;
#pragma unroll
    for (int i = 0; i < 64; ++i) {
        int k = l8 + i * 8;
        p += xsh[tt][k] * g_w[hh * D_ + k];
    }
    p += __shfl_xor(p, 1);
    p += __shfl_xor(p, 2);
    p += __shfl_xor(p, 4);
    if (l8 == 0) logits[tt][hh] = p + g_b[hh];
    __syncthreads();
    // softmax per token (redundant in its wave) + head-mix -> hd[tt][lane]
    {
        int lane = tid & 63;
        float m = logits[tt][0];
#pragma unroll
        for (int h = 1; h < H_; ++h) m = fmaxf(m, logits[tt][h]);
        float e[H_];
        float sum = 0.f;
#pragma unroll
        for (int h = 0; h < H_; ++h) { e[h] = expf(logits[tt][h] - m); sum += e[h]; }
        float inv = 1.f / sum;
        float v = 0.f;
#pragma unroll
        for (int h = 0; h < H_; ++h) v += e[h] * inv * xsh[tt][h * HD_ + lane];
        hd[tt][lane] = v;
    }
    __syncthreads();
    // Phase A2: xs[t] = hd[t] @ spT + sp_b, thread owns cols (2tid, 2tid+1)
    {
        float2 bv = ((const float2*)sp_b)[tid];
        float2 acc[4] = {bv, bv, bv, bv};
        const float2* spT2 = (const float2*)spT;
        for (int k = 0; k < HD_; ++k) {
            float2 w = spT2[k * 256 + tid];
#pragma unroll
            for (int t = 0; t < 4; ++t) {
                float hk = hd[t][k];
                acc[t].x += hk * w.x;
                acc[t].y += hk * w.y;
            }
        }
#pragma unroll
        for (int t = 0; t < 4; ++t) {
            ((float2*)&xss[t][0])[tid] = acc[t];
            ((float2*)xs)[(size_t)(t0 + t) * 256 + tid] = acc[t];
        }
    }
    __syncthreads();
    // Phase B: gate GEMM from LDS xss
    {
        float2 bv = ((const float2*)gate_b)[tid];
        float2 acc[4] = {bv, bv, bv, bv};
        const float2* gT2 = (const float2*)gT;
        for (int k0 = 0; k0 < D_; k0 += 4) {
            float2 w0 = gT2[(k0 + 0) * 256 + tid];
            float2 w1 = gT2[(k0 + 1) * 256 + tid];
            float2 w2 = gT2[(k0 + 2) * 256 + tid];
            float2 w3 = gT2[(k0 + 3) * 256 + tid];
#pragma unroll
            for (int j = 0; j < 4; ++j) {
                float4 xv = *(const float4*)&xss[j][k0];
                acc[j].x += xv.x * w0.x + xv.y * w1.x + xv.z * w2.x + xv.w * w3.x;
                acc[j].y += xv.x * w0.y + xv.y * w1.y + xv.z * w2.y + xv.w * w3.y;
            }
        }
#pragma unroll
        for (int j = 0; j < 4; ++j) {
            float2 o;
            o.x = 1.f / (1.f + expf(-acc[j].x));
            o.y = 1.f / (1.f + expf(-acc[j].y));
            ((float2*)gate)[(size_t)(t0 + j) * 256 + tid] = o;
        }
    }
}

// ------------------------------------------------------- scores Gram matrix
// scores[b,i,j] = sqrt(sum_d gate[b,i,d]^2 gate[b,j,d]^2); 64x64 tile, 4x4/thread
__global__ __launch_bounds__(256) void k_scores(const float* __restrict__ gate,
                                                float* __restrict__ scores) {
    int b = blockIdx.z;
    int i0 = blockIdx.y * 64, j0 = blockIdx.x * 64;
    int tid = threadIdx.x;
    int tx = tid & 15, ty = tid >> 4;
    __shared__ float Ash[16][68];
    __shared__ float Bsh[16][68];
    float acc[4][4];
#pragma unroll
    for (int r = 0; r < 4; ++r)
#pragma unroll
        for (int c = 0; c < 4; ++c) acc[r][c] = 0.f;
    const float* gb = gate + (size_t)b * T_ * D_;
    int sr = tid >> 2, sc4 = (tid & 3) * 4;
    for (int k0 = 0; k0 < D_; k0 += 16) {
        float4 av = *(const float4*)&gb[(size_t)(i0 + sr) * D_ + k0 + sc4];
        float4 bvv = *(const float4*)&gb[(size_t)(j0 + sr) * D_ + k0 + sc4];
        Ash[sc4 + 0][sr] = av.x * av.x;
        Ash[sc4 + 1][sr] = av.y * av.y;
        Ash[sc4 + 2][sr] = av.z * av.z;
        Ash[sc4 + 3][sr] = av.w * av.w;
        Bsh[sc4 + 0][sr] = bvv.x * bvv.x;
        Bsh[sc4 + 1][sr] = bvv.y * bvv.y;
        Bsh[sc4 + 2][sr] = bvv.z * bvv.z;
        Bsh[sc4 + 3][sr] = bvv.w * bvv.w;
        __syncthreads();
#pragma unroll
        for (int kk = 0; kk < 16; ++kk) {
            float4 a4 = *(const float4*)&Ash[kk][4 * ty];
            float4 b4 = *(const float4*)&Bsh[kk][4 * tx];
            float ar[4] = {a4.x, a4.y, a4.z, a4.w};
            float bc[4] = {b4.x, b4.y, b4.z, b4.w};
#pragma unroll
            for (int r = 0; r < 4; ++r)
#pragma unroll
                for (int c = 0; c < 4; ++c) acc[r][c] += ar[r] * bc[c];
        }
        __syncthreads();
    }
#pragma unroll
    for (int r = 0; r < 4; ++r) {
        float4 o;
        o.x = sqrtf(acc[r][0]);
        o.y = sqrtf(acc[r][1]);
        o.z = sqrtf(acc[r][2]);
        o.w = sqrtf(acc[r][3]);
        *(float4*)&scores[((size_t)b * T_ + (i0 + 4 * ty + r)) * T_ + j0 + 4 * tx] = o;
    }
}

// ------------------------- fused top-K + entangle + U GEMM + LayerNorm
// Phase 1: wave-per-row iterative argmax (ties -> lower index, JAX semantics);
//          x_out = xs + gate_i * sum_sel gate_j  staged into LDS.
// Phase 2: out = LN(x_out @ uT + U_b) * ln_g + ln_b.
__global__ __launch_bounds__(256) void k_topk_out(
    const float* __restrict__ scores, const float* __restrict__ gate,
    const float* __restrict__ xs, const float* __restrict__ uT,
    const float* __restrict__ U_b, const float* __restrict__ ln_g,
    const float* __restrict__ ln_b, float* __restrict__ out) {
    int tid = threadIdx.x;
    int wave = tid >> 6, lane = tid & 63;
    int t0 = blockIdx.x * 4;
    int row = t0 + wave;
    int b = row / T_;
    __shared__ float xo[4][D_];
    __shared__ float2 red4[4];
    // ---- phase 1: top-K selection ----
    const float* srow = scores + (size_t)row * T_;
    float v[6];
#pragma unroll
    for (int q = 0; q < 6; ++q) v[q] = srow[q * 64 + lane];
    int keep = 0;  // lane 'it' holds selected index of iteration 'it'
    for (int it = 0; it < K_; ++it) {
        float bv = v[0];
        int bq = 0;
#pragma unroll
        for (int q = 1; q < 6; ++q)
            if (v[q] > bv) { bv = v[q]; bq = q; }  // strict > : lower q wins ties
        int bidx = bq * 64 + lane;
#pragma unroll
        for (int off = 1; off < 64; off <<= 1) {
            float ov = __shfl_xor(bv, off);
            int oi = __shfl_xor(bidx, off);
            if (ov > bv || (ov == bv && oi < bidx)) { bv = ov; bidx = oi; }
        }
        if (lane == (bidx & 63)) v[bidx >> 6] = -FLT_MAX;
        if (lane == it) keep = bidx;
    }
    // ---- entangle into LDS ----
    float4 s0 = {0.f, 0.f, 0.f, 0.f}, s1 = {0.f, 0.f, 0.f, 0.f};
    const float* gb = gate + (size_t)b * T_ * D_;
    for (int n = 0; n < K_; ++n) {
        int j = __shfl(keep, n);
        const float4* gj = (const float4*)(gb + (size_t)j * D_ + lane * 8);
        float4 g0 = gj[0], g1 = gj[1];
        s0.x += g0.x; s0.y += g0.y; s0.z += g0.z; s0.w += g0.w;
        s1.x += g1.x; s1.y += g1.y; s1.z += g1.z; s1.w += g1.w;
    }
    size_t base = (size_t)row * D_ + lane * 8;
    const float4* gi = (const float4*)(gate + base);
    const float4* xi = (const float4*)(xs + base);
    float4 gi0 = gi[0], gi1 = gi[1];
    float4 x0 = xi[0], x1 = xi[1];
    x0.x += gi0.x * s0.x; x0.y += gi0.y * s0.y; x0.z += gi0.z * s0.z; x0.w += gi0.w * s0.w;
    x1.x += gi1.x * s1.x; x1.y += gi1.y * s1.y; x1.z += gi1.z * s1.z; x1.w += gi1.w * s1.w;
    *(float4*)&xo[wave][lane * 8] = x0;
    *(float4*)&xo[wave][lane * 8 + 4] = x1;
    __syncthreads();
    // ---- phase 2: U GEMM + LayerNorm ----
    float2 bv2 = ((const float2*)U_b)[tid];
    float2 acc[4] = {bv2, bv2, bv2, bv2};
    const float2* uT2 = (const float2*)uT;
    for (int k0 = 0; k0 < D_; k0 += 4) {
        float2 w0 = uT2[(k0 + 0) * 256 + tid];
        float2 w1 = uT2[(k0 + 1) * 256 + tid];
        float2 w2 = uT2[(k0 + 2) * 256 + tid];
        float2 w3 = uT2[(k0 + 3) * 256 + tid];
#pragma unroll
        for (int j = 0; j < 4; ++j) {
            float4 xv = *(const float4*)&xo[j][k0];
            acc[j].x += xv.x * w0.x + xv.y * w1.x + xv.z * w2.x + xv.w * w3.x;
            acc[j].y += xv.x * w0.y + xv.y * w1.y + xv.z * w2.y + xv.w * w3.y;
        }
    }
    float2 lg = ((const float2*)ln_g)[tid];
    float2 lb = ((const float2*)ln_b)[tid];
#pragma unroll
    for (int j = 0; j < 4; ++j) {
        float2 a = acc[j];
        float2 sv;
        sv.x = a.x + a.y;
        sv.y = a.x * a.x + a.y * a.y;
#pragma unroll
        for (int off = 32; off > 0; off >>= 1) {
            sv.x += __shfl_xor(sv.x, off);
            sv.y += __shfl_xor(sv.y, off);
        }
        if (lane == 0) red4[wave] = sv;
        __syncthreads();
        float m1 = red4[0].x + red4[1].x + red4[2].x + red4[3].x;
        float m2 = red4[0].y + red4[1].y + red4[2].y + red4[3].y;
        __syncthreads();
        float mu = m1 * (1.f / D_);
        float var = fmaxf(m2 * (1.f / D_) - mu * mu, 0.f);
        float inv = rsqrtf(var + LN_EPS);
        float2 o;
        o.x = lg.x * (a.x - mu) * inv + lb.x;
        o.y = lg.y * (a.y - mu) * inv + lb.y;
        ((float2*)out)[(size_t)(t0 + j) * 256 + tid] = o;
    }
}

// --------------------------------------------------------------------- launch
extern "C" void kernel_launch(void* const* d_in, const int* in_sizes, int n_in,
                              void* d_out, int out_size, void* d_ws, size_t ws_size,
                              hipStream_t stream) {
    const float* x      = (const float*)d_in[0];
    const float* g_w    = (const float*)d_in[1];
    const float* g_b    = (const float*)d_in[2];
    const float* sp_w   = (const float*)d_in[3];
    const float* sp_b   = (const float*)d_in[4];
    const float* gate_w = (const float*)d_in[5];
    const float* gate_b = (const float*)d_in[6];
    const float* U_w    = (const float*)d_in[7];
    const float* U_b    = (const float*)d_in[8];
    const float* ln_g   = (const float*)d_in[9];
    const float* ln_b   = (const float*)d_in[10];

    float* ws     = (float*)d_ws;
    float* gT     = ws;                 // 512*512
    float* uT     = gT + 262144;        // 512*512
    float* spT    = uT + 262144;        // 64*512
    float* xs     = spT + 32768;        // 768*512 (x_super)
    float* gate   = xs + 393216;        // 768*512
    float* scores = gate + 393216;      // 2*384*384

    k_prep<<<544, 256, 0, stream>>>(gate_w, U_w, sp_w, gT, uT, spT);
    k_super_gate<<<B_ * T_ / 4, 256, 0, stream>>>(x, g_w, g_b, spT, sp_b, gT,
                                                  gate_b, xs, gate);
    k_scores<<<dim3(T_ / 64, T_ / 64, B_), 256, 0, stream>>>(gate, scores);
    k_topk_out<<<B_ * T_ / 4, 256, 0, stream>>>(scores, gate, xs, uT, U_b,
                                                ln_g, ln_b, (float*)d_out);
}

// Round 6
// 211.176 us; speedup vs baseline: 1.1596x; 1.0129x over previous
//
#include <hip/hip_runtime.h>
#include <math.h>
#include <float.h>

#define B_ 2
#define T_ 384
#define D_ 512
#define H_ 8
#define HD_ 64
#define K_ 48
#define LN_EPS 1e-5f

// ----------------------------------------------- coalesced tiled transposes
__global__ __launch_bounds__(256) void k_prep(const float* __restrict__ gate_w,
                                              const float* __restrict__ U_w,
                                              const float* __restrict__ sp_w,
                                              float* __restrict__ gT,
                                              float* __restrict__ uT,
                                              float* __restrict__ spT) {
    __shared__ float t[32][33];
    int bid = blockIdx.x;
    const float* src;
    float* dst;
    int C, tr, tc;
    if (bid < 256) {
        src = gate_w; dst = gT; C = 512; tr = bid >> 4; tc = bid & 15;
    } else if (bid < 512) {
        int b2 = bid - 256;
        src = U_w; dst = uT; C = 512; tr = b2 >> 4; tc = b2 & 15;
    } else {
        int b3 = bid - 512;
        src = sp_w; dst = spT; C = 64; tr = b3 >> 1; tc = b3 & 1;
    }
    int r0 = tr * 32, c0 = tc * 32;
    int tx = threadIdx.x & 31, ty = threadIdx.x >> 5;
#pragma unroll
    for (int i = 0; i < 4; ++i)
        t[ty + 8 * i][tx] = src[(size_t)(r0 + ty + 8 * i) * C + c0 + tx];
    __syncthreads();
#pragma unroll
    for (int i = 0; i < 4; ++i)
        dst[(size_t)(c0 + ty + 8 * i) * 512 + r0 + tx] = t[tx][ty + 8 * i];
}

// --------------------------------- fused superposition + gate (4 tokens/block)
__global__ __launch_bounds__(256) void k_super_gate(
    const float* __restrict__ x, const float* __restrict__ g_w,
    const float* __restrict__ g_b, const float* __restrict__ spT,
    const float* __restrict__ sp_b, const float* __restrict__ gT,
    const float* __restrict__ gate_b, float* __restrict__ xs,
    float* __restrict__ gate) {
    int t0 = blockIdx.x * 4;
    int tid = threadIdx.x;
    __shared__ float xsh[4][D_];
    __shared__ float xss[4][D_];
    __shared__ float logits[4][H_];
    __shared__ float hd[4][HD_];
    ((float4*)&xsh[0][0])[tid] = ((const float4*)(x + (size_t)t0 * D_))[tid];
    ((float4*)&xsh[0][0])[tid + 256] = ((const float4*)(x + (size_t)t0 * D_))[tid + 256];
    __syncthreads();
    int tt = tid >> 6, hh = (tid >> 3) & 7, l8 = tid & 7;
    float p = 0.f;
#pragma unroll
    for (int i = 0; i < 64; ++i) {
        int k = l8 + i * 8;
        p += xsh[tt][k] * g_w[hh * D_ + k];
    }
    p += __shfl_xor(p, 1);
    p += __shfl_xor(p, 2);
    p += __shfl_xor(p, 4);
    if (l8 == 0) logits[tt][hh] = p + g_b[hh];
    __syncthreads();
    {
        int lane = tid & 63;
        float m = logits[tt][0];
#pragma unroll
        for (int h = 1; h < H_; ++h) m = fmaxf(m, logits[tt][h]);
        float e[H_];
        float sum = 0.f;
#pragma unroll
        for (int h = 0; h < H_; ++h) { e[h] = expf(logits[tt][h] - m); sum += e[h]; }
        float inv = 1.f / sum;
        float v = 0.f;
#pragma unroll
        for (int h = 0; h < H_; ++h) v += e[h] * inv * xsh[tt][h * HD_ + lane];
        hd[tt][lane] = v;
    }
    __syncthreads();
    {
        float2 bv = ((const float2*)sp_b)[tid];
        float2 acc[4] = {bv, bv, bv, bv};
        const float2* spT2 = (const float2*)spT;
        for (int k = 0; k < HD_; ++k) {
            float2 w = spT2[k * 256 + tid];
#pragma unroll
            for (int t = 0; t < 4; ++t) {
                float hk = hd[t][k];
                acc[t].x += hk * w.x;
                acc[t].y += hk * w.y;
            }
        }
#pragma unroll
        for (int t = 0; t < 4; ++t) {
            ((float2*)&xss[t][0])[tid] = acc[t];
            ((float2*)xs)[(size_t)(t0 + t) * 256 + tid] = acc[t];
        }
    }
    __syncthreads();
    {
        float2 bv = ((const float2*)gate_b)[tid];
        float2 acc[4] = {bv, bv, bv, bv};
        const float2* gT2 = (const float2*)gT;
        for (int k0 = 0; k0 < D_; k0 += 4) {
            float2 w0 = gT2[(k0 + 0) * 256 + tid];
            float2 w1 = gT2[(k0 + 1) * 256 + tid];
            float2 w2 = gT2[(k0 + 2) * 256 + tid];
            float2 w3 = gT2[(k0 + 3) * 256 + tid];
#pragma unroll
            for (int j = 0; j < 4; ++j) {
                float4 xv = *(const float4*)&xss[j][k0];
                acc[j].x += xv.x * w0.x + xv.y * w1.x + xv.z * w2.x + xv.w * w3.x;
                acc[j].y += xv.x * w0.y + xv.y * w1.y + xv.z * w2.y + xv.w * w3.y;
            }
        }
#pragma unroll
        for (int j = 0; j < 4; ++j) {
            float2 o;
            o.x = 1.f / (1.f + expf(-acc[j].x));
            o.y = 1.f / (1.f + expf(-acc[j].y));
            ((float2*)gate)[(size_t)(t0 + j) * 256 + tid] = o;
        }
    }
}

// ------------------------------------------------------- scores Gram matrix
__global__ __launch_bounds__(256) void k_scores(const float* __restrict__ gate,
                                                float* __restrict__ scores) {
    int b = blockIdx.z;
    int i0 = blockIdx.y * 64, j0 = blockIdx.x * 64;
    int tid = threadIdx.x;
    int tx = tid & 15, ty = tid >> 4;
    __shared__ float Ash[16][68];
    __shared__ float Bsh[16][68];
    float acc[4][4];
#pragma unroll
    for (int r = 0; r < 4; ++r)
#pragma unroll
        for (int c = 0; c < 4; ++c) acc[r][c] = 0.f;
    const float* gb = gate + (size_t)b * T_ * D_;
    int sr = tid >> 2, sc4 = (tid & 3) * 4;
    for (int k0 = 0; k0 < D_; k0 += 16) {
        float4 av = *(const float4*)&gb[(size_t)(i0 + sr) * D_ + k0 + sc4];
        float4 bvv = *(const float4*)&gb[(size_t)(j0 + sr) * D_ + k0 + sc4];
        Ash[sc4 + 0][sr] = av.x * av.x;
        Ash[sc4 + 1][sr] = av.y * av.y;
        Ash[sc4 + 2][sr] = av.z * av.z;
        Ash[sc4 + 3][sr] = av.w * av.w;
        Bsh[sc4 + 0][sr] = bvv.x * bvv.x;
        Bsh[sc4 + 1][sr] = bvv.y * bvv.y;
        Bsh[sc4 + 2][sr] = bvv.z * bvv.z;
        Bsh[sc4 + 3][sr] = bvv.w * bvv.w;
        __syncthreads();
#pragma unroll
        for (int kk = 0; kk < 16; ++kk) {
            float4 a4 = *(const float4*)&Ash[kk][4 * ty];
            float4 b4 = *(const float4*)&Bsh[kk][4 * tx];
            float ar[4] = {a4.x, a4.y, a4.z, a4.w};
            float bc[4] = {b4.x, b4.y, b4.z, b4.w};
#pragma unroll
            for (int r = 0; r < 4; ++r)
#pragma unroll
                for (int c = 0; c < 4; ++c) acc[r][c] += ar[r] * bc[c];
        }
        __syncthreads();
    }
#pragma unroll
    for (int r = 0; r < 4; ++r) {
        float4 o;
        o.x = sqrtf(acc[r][0]);
        o.y = sqrtf(acc[r][1]);
        o.z = sqrtf(acc[r][2]);
        o.w = sqrtf(acc[r][3]);
        *(float4*)&scores[((size_t)b * T_ + (i0 + 4 * ty + r)) * T_ + j0 + 4 * tx] = o;
    }
}

// -------------------------------------------- top-K selection only (no barriers)
// wave-per-row iterative argmax, ties -> lower index (JAX). sel gets ABSOLUTE row.
__global__ __launch_bounds__(256) void k_topk(const float* __restrict__ scores,
                                              int* __restrict__ sel) {
    int tid = threadIdx.x;
    int wave = tid >> 6, lane = tid & 63;
    int row = blockIdx.x * 4 + wave;          // 0..767
    int b = row / T_;
    const float* srow = scores + (size_t)row * T_;
    float v[6];
#pragma unroll
    for (int q = 0; q < 6; ++q) v[q] = srow[q * 64 + lane];
    int keep = 0;
    for (int it = 0; it < K_; ++it) {
        float bv = v[0];
        int bq = 0;
#pragma unroll
        for (int q = 1; q < 6; ++q)
            if (v[q] > bv) { bv = v[q]; bq = q; }  // strict > : lower q wins ties
        int bidx = bq * 64 + lane;
#pragma unroll
        for (int off = 1; off < 64; off <<= 1) {
            float ov = __shfl_xor(bv, off);
            int oi = __shfl_xor(bidx, off);
            if (ov > bv || (ov == bv && oi < bidx)) { bv = ov; bidx = oi; }
        }
        if (lane == (bidx & 63)) v[bidx >> 6] = -FLT_MAX;
        if (lane == it) keep = bidx;
    }
    if (lane < K_) sel[row * K_ + lane] = b * T_ + keep;
}

// ---------------------------------------- entangle: xo = xs + gate .* sum(gate[sel])
// one row per block; thread owns 2 adjacent cols; 48 independent gathers.
__global__ __launch_bounds__(256) void k_ent(const int* __restrict__ sel,
                                             const float* __restrict__ gate,
                                             const float* __restrict__ xs,
                                             float* __restrict__ xo) {
    int row = blockIdx.x;
    int tid = threadIdx.x;
    __shared__ int ssel[K_];
    if (tid < K_) ssel[tid] = sel[row * K_ + tid];
    __syncthreads();
    const float2* g2 = (const float2*)gate;
    float2 s = {0.f, 0.f};
#pragma unroll 8
    for (int n = 0; n < K_; ++n) {
        float2 g = g2[(size_t)ssel[n] * 256 + tid];
        s.x += g.x;
        s.y += g.y;
    }
    float2 gi = g2[(size_t)row * 256 + tid];
    float2 xv = ((const float2*)xs)[(size_t)row * 256 + tid];
    float2 o;
    o.x = xv.x + gi.x * s.x;
    o.y = xv.y + gi.y * s.y;
    ((float2*)xo)[(size_t)row * 256 + tid] = o;
}

// ------------------------------------------- y = xo @ uT + U_b (tiled GEMM)
// 32 rows x 64 cols per block, grid (8 col-tiles, 24 row-tiles), 256 threads,
// each thread 2 rows x 4 cols. LDS-staged A/B chunks of K=32.
__global__ __launch_bounds__(256) void k_y(const float* __restrict__ xo,
                                           const float* __restrict__ uT,
                                           const float* __restrict__ U_b,
                                           float* __restrict__ y) {
    int c0 = blockIdx.x * 64, r0 = blockIdx.y * 32;
    int tid = threadIdx.x;
    int ry = tid >> 4, cx = tid & 15;
    __shared__ float A_sh[32][33];
    __shared__ float B_sh[32][64];
    float acc[2][4];
#pragma unroll
    for (int r = 0; r < 2; ++r)
#pragma unroll
        for (int c = 0; c < 4; ++c) acc[r][c] = 0.f;
    int ar = tid >> 3, ac = (tid & 7) * 4;       // A stage coords
    int br = tid >> 3, bc = (tid & 7) * 8;       // B stage coords
    for (int k0 = 0; k0 < D_; k0 += 32) {
        float4 a4 = *(const float4*)&xo[(size_t)(r0 + ar) * D_ + k0 + ac];
        A_sh[ar][ac + 0] = a4.x;
        A_sh[ar][ac + 1] = a4.y;
        A_sh[ar][ac + 2] = a4.z;
        A_sh[ar][ac + 3] = a4.w;
        *(float4*)&B_sh[br][bc] = *(const float4*)&uT[(size_t)(k0 + br) * D_ + c0 + bc];
        *(float4*)&B_sh[br][bc + 4] = *(const float4*)&uT[(size_t)(k0 + br) * D_ + c0 + bc + 4];
        __syncthreads();
#pragma unroll
        for (int kk = 0; kk < 32; ++kk) {
            float4 bv = *(const float4*)&B_sh[kk][cx * 4];
            float a0 = A_sh[ry * 2][kk];
            float a1 = A_sh[ry * 2 + 1][kk];
            acc[0][0] += a0 * bv.x; acc[0][1] += a0 * bv.y;
            acc[0][2] += a0 * bv.z; acc[0][3] += a0 * bv.w;
            acc[1][0] += a1 * bv.x; acc[1][1] += a1 * bv.y;
            acc[1][2] += a1 * bv.z; acc[1][3] += a1 * bv.w;
        }
        __syncthreads();
    }
    float4 ub = *(const float4*)&U_b[c0 + cx * 4];
#pragma unroll
    for (int r = 0; r < 2; ++r) {
        float4 o;
        o.x = acc[r][0] + ub.x;
        o.y = acc[r][1] + ub.y;
        o.z = acc[r][2] + ub.z;
        o.w = acc[r][3] + ub.w;
        *(float4*)&y[(size_t)(r0 + ry * 2 + r) * D_ + c0 + cx * 4] = o;
    }
}

// ------------------------------------------------------------- LayerNorm
__global__ __launch_bounds__(256) void k_ln(const float* __restrict__ y,
                                            const float* __restrict__ ln_g,
                                            const float* __restrict__ ln_b,
                                            float* __restrict__ out) {
    int t0 = blockIdx.x * 4;
    int tid = threadIdx.x;
    int wave = tid >> 6, lane = tid & 63;
    __shared__ float2 red4[4];
    float2 lg = ((const float2*)ln_g)[tid];
    float2 lb = ((const float2*)ln_b)[tid];
#pragma unroll
    for (int j = 0; j < 4; ++j) {
        float2 a = ((const float2*)y)[(size_t)(t0 + j) * 256 + tid];
        float2 sv;
        sv.x = a.x + a.y;
        sv.y = a.x * a.x + a.y * a.y;
#pragma unroll
        for (int off = 32; off > 0; off >>= 1) {
            sv.x += __shfl_xor(sv.x, off);
            sv.y += __shfl_xor(sv.y, off);
        }
        if (lane == 0) red4[wave] = sv;
        __syncthreads();
        float m1 = red4[0].x + red4[1].x + red4[2].x + red4[3].x;
        float m2 = red4[0].y + red4[1].y + red4[2].y + red4[3].y;
        __syncthreads();
        float mu = m1 * (1.f / D_);
        float var = fmaxf(m2 * (1.f / D_) - mu * mu, 0.f);
        float inv = rsqrtf(var + LN_EPS);
        float2 o;
        o.x = lg.x * (a.x - mu) * inv + lb.x;
        o.y = lg.y * (a.y - mu) * inv + lb.y;
        ((float2*)out)[(size_t)(t0 + j) * 256 + tid] = o;
    }
}

// --------------------------------------------------------------------- launch
extern "C" void kernel_launch(void* const* d_in, const int* in_sizes, int n_in,
                              void* d_out, int out_size, void* d_ws, size_t ws_size,
                              hipStream_t stream) {
    const float* x      = (const float*)d_in[0];
    const float* g_w    = (const float*)d_in[1];
    const float* g_b    = (const float*)d_in[2];
    const float* sp_w   = (const float*)d_in[3];
    const float* sp_b   = (const float*)d_in[4];
    const float* gate_w = (const float*)d_in[5];
    const float* gate_b = (const float*)d_in[6];
    const float* U_w    = (const float*)d_in[7];
    const float* U_b    = (const float*)d_in[8];
    const float* ln_g   = (const float*)d_in[9];
    const float* ln_b   = (const float*)d_in[10];

    float* ws     = (float*)d_ws;
    float* gT     = ws;                 // 512*512
    float* uT     = gT + 262144;        // 512*512
    float* spT    = uT + 262144;        // 64*512
    float* xs     = spT + 32768;        // 768*512
    float* gate   = xs + 393216;        // 768*512
    float* scores = gate + 393216;      // 2*384*384
    float* xo     = scores + 294912;    // 768*512
    float* yb     = xo + 393216;        // 768*512
    int*   sel    = (int*)(yb + 393216); // 768*48

    k_prep<<<544, 256, 0, stream>>>(gate_w, U_w, sp_w, gT, uT, spT);
    k_super_gate<<<B_ * T_ / 4, 256, 0, stream>>>(x, g_w, g_b, spT, sp_b, gT,
                                                  gate_b, xs, gate);
    k_scores<<<dim3(T_ / 64, T_ / 64, B_), 256, 0, stream>>>(gate, scores);
    k_topk<<<B_ * T_ / 4, 256, 0, stream>>>(scores, sel);
    k_ent<<<B_ * T_, 256, 0, stream>>>(sel, gate, xs, xo);
    k_y<<<dim3(D_ / 64, B_ * T_ / 32), 256, 0, stream>>>(xo, uT, U_b, yb);
    k_ln<<<B_ * T_ / 4, 256, 0, stream>>>(yb, ln_g, ln_b, (float*)d_out);
}